// Round 17
// baseline (74.690 us; speedup 1.0000x reference)
//
#include <hip/hip_runtime.h>

#define B_ 2048
#define S_ 512
#define T_ 17
#define RECN 256
#define FWDW 448          // 7 segments x 64 waves (fwd F0..F6)
#define MAINW 896         // + 7 segments x 64 waves (bwd G1..G7)

typedef float v16f __attribute__((ext_vector_type(16)));
typedef short v8s  __attribute__((ext_vector_type(8)));
typedef float f4u  __attribute__((ext_vector_type(4), aligned(4)));

union frag_u { unsigned u[4]; v8s v; };

static __device__ inline unsigned pkbf(float lo, float hi) {
    unsigned r;
    asm("v_cvt_pk_bf16_f32 %0, %1, %2" : "=v"(r) : "v"(lo), "v"(hi));
    return r;
}

#define PACKB(S0,S1,S2,S3,S4,S5,S6,S7, BOUT) do {                            \
    unsigned P0_ = pkbf(S0, S1), P1_ = pkbf(S2, S3);                         \
    unsigned R0_ = pkbf(S4, S5), R1_ = pkbf(S6, S7);                         \
    auto s0_ = __builtin_amdgcn_permlane32_swap(P0_, R0_, false, false);     \
    auto s1_ = __builtin_amdgcn_permlane32_swap(P1_, R1_, false, false);     \
    BOUT.u[0] = s0_[0]; BOUT.u[1] = s1_[0];                                  \
    BOUT.u[2] = s0_[1]; BOUT.u[3] = s1_[1];                                  \
} while (0)

#define W16SWAP() do {                                                       \
    auto rw_ = __builtin_amdgcn_permlane32_swap(__float_as_uint(W8),         \
                                                __float_as_uint(W8),         \
                                                false, false);               \
    w16 = __uint_as_float(rw_[0]);                                           \
} while (0)

#define LOADK8(Q0, Q1, SS, MA, MB, T0_) do {                                 \
    const float* bp_ = ip + (size_t)(T0_) * T_;                              \
    _Pragma("unroll") for (int u_ = 0; u_ < 8; ++u_) {                       \
        Q0[u_] = *(const f4u*)(bp_ + u_ * T_ + 4 * h);                       \
        Q1[u_] = *(const f4u*)(bp_ + u_ * T_ + 8 + 4 * h);                   \
        SS[u_] = bp_[u_ * T_ + 16];                                          \
    }                                                                        \
    MA = *(const int4*)(mp + (T0_));                                         \
    MB = *(const int4*)(mp + (T0_) + 4);                                     \
} while (0)

#define FSTEP(Q0u, Q1u, Su, Mu) do {                                         \
    frag_u Bf_;                                                              \
    PACKB(W0,W1,W2,W3,W4,W5,W6,W7, Bf_);                                     \
    v16f acc_ = __builtin_amdgcn_mfma_f32_32x32x16_bf16(A1.v, Bf_.v, zacc,0,0,0); \
    float d0_=__expf((Q0u).x), d1_=__expf((Q0u).y);                          \
    float d2_=__expf((Q0u).z), d3_=__expf((Q0u).w);                          \
    float d4_=__expf((Q1u).x), d5_=__expf((Q1u).y);                          \
    float d6_=__expf((Q1u).z), d7_=__expf((Q1u).w);                          \
    float d8_=__expf(Su);                                                    \
    bool bm_ = (Mu) != 0;                                                    \
    float n0_ = fmaf(E16[0], w16, acc_[0]) * d0_;                            \
    float n1_ = fmaf(E16[1], w16, acc_[1]) * d1_;                            \
    float n2_ = fmaf(E16[2], w16, acc_[2]) * d2_;                            \
    float n3_ = fmaf(E16[3], w16, acc_[3]) * d3_;                            \
    float n4_ = fmaf(E16[4], w16, acc_[4]) * d4_;                            \
    float n5_ = fmaf(E16[5], w16, acc_[5]) * d5_;                            \
    float n6_ = fmaf(E16[6], w16, acc_[6]) * d6_;                            \
    float n7_ = fmaf(E16[7], w16, acc_[7]) * d7_;                            \
    float n8_ = fmaf(E16[8], w16, acc_[8]) * d8_;                            \
    W0=bm_?n0_:W0; W1=bm_?n1_:W1; W2=bm_?n2_:W2; W3=bm_?n3_:W3;              \
    W4=bm_?n4_:W4; W5=bm_?n5_:W5; W6=bm_?n6_:W6; W7=bm_?n7_:W7;              \
    W8=bm_?n8_:W8;                                                           \
    W16SWAP();                                                               \
} while (0)

#define BSTEP(Q0u, Q1u, Su, Mu) do {                                         \
    float d0_=__expf((Q0u).x), d1_=__expf((Q0u).y);                          \
    float d2_=__expf((Q0u).z), d3_=__expf((Q0u).w);                          \
    float d4_=__expf((Q1u).x), d5_=__expf((Q1u).y);                          \
    float d6_=__expf((Q1u).z), d7_=__expf((Q1u).w);                          \
    float d8_=__expf(Su);                                                    \
    float U16_ = w16 * d8_;                                                  \
    frag_u Bf_;                                                              \
    PACKB(W0*d0_, W1*d1_, W2*d2_, W3*d3_,                                    \
          W4*d4_, W5*d5_, W6*d6_, W7*d7_, Bf_);                              \
    v16f acc_ = __builtin_amdgcn_mfma_f32_32x32x16_bf16(A1.v, Bf_.v, zacc,0,0,0); \
    bool bm_ = (Mu) != 0;                                                    \
    float n0_ = fmaf(E16[0], U16_, acc_[0]);                                 \
    float n1_ = fmaf(E16[1], U16_, acc_[1]);                                 \
    float n2_ = fmaf(E16[2], U16_, acc_[2]);                                 \
    float n3_ = fmaf(E16[3], U16_, acc_[3]);                                 \
    float n4_ = fmaf(E16[4], U16_, acc_[4]);                                 \
    float n5_ = fmaf(E16[5], U16_, acc_[5]);                                 \
    float n6_ = fmaf(E16[6], U16_, acc_[6]);                                 \
    float n7_ = fmaf(E16[7], U16_, acc_[7]);                                 \
    float n8_ = fmaf(E16[8], U16_, acc_[8]);                                 \
    W0=bm_?n0_:W0; W1=bm_?n1_:W1; W2=bm_?n2_:W2; W3=bm_?n3_:W3;              \
    W4=bm_?n4_:W4; W5=bm_?n5_:W5; W6=bm_?n6_:W6; W7=bm_?n7_:W7;              \
    W8=bm_?n8_:W8;                                                           \
    W16SWAP();                                                               \
} while (0)

#define RENORM() do {                                                        \
    float M_ = fmaxf(fmaxf(fmaxf(W0,W1),fmaxf(W2,W3)),                       \
                     fmaxf(fmaxf(W4,W5),fmaxf(fmaxf(W6,W7),W8)));            \
    auto rm_ = __builtin_amdgcn_permlane32_swap(__float_as_uint(M_),         \
                                                __float_as_uint(M_),         \
                                                false, false);               \
    M_ = fmaxf(__uint_as_float(rm_[0]), __uint_as_float(rm_[1]));            \
    float r_ = 1.0f / M_;                                                    \
    Z += __logf(M_);                                                         \
    W0*=r_; W1*=r_; W2*=r_; W3*=r_; W4*=r_;                                  \
    W5*=r_; W6*=r_; W7*=r_; W8*=r_; w16*=r_;                                 \
} while (0)

#define FCH8(Q0a, Q1a, Sa, Ma, Mb) do {                                      \
    FSTEP(Q0a[0], Q1a[0], Sa[0], (Ma).x);                                    \
    FSTEP(Q0a[1], Q1a[1], Sa[1], (Ma).y);                                    \
    FSTEP(Q0a[2], Q1a[2], Sa[2], (Ma).z);                                    \
    FSTEP(Q0a[3], Q1a[3], Sa[3], (Ma).w);                                    \
    RENORM();                                                                \
    FSTEP(Q0a[4], Q1a[4], Sa[4], (Mb).x);                                    \
    FSTEP(Q0a[5], Q1a[5], Sa[5], (Mb).y);                                    \
    FSTEP(Q0a[6], Q1a[6], Sa[6], (Mb).z);                                    \
    FSTEP(Q0a[7], Q1a[7], Sa[7], (Mb).w);                                    \
    RENORM();                                                                \
} while (0)

#define BCH8(Q0a, Q1a, Sa, Ma, Mb) do {                                      \
    BSTEP(Q0a[7], Q1a[7], Sa[7], (Mb).w);                                    \
    BSTEP(Q0a[6], Q1a[6], Sa[6], (Mb).z);                                    \
    BSTEP(Q0a[5], Q1a[5], Sa[5], (Mb).y);                                    \
    BSTEP(Q0a[4], Q1a[4], Sa[4], (Mb).x);                                    \
    RENORM();                                                                \
    BSTEP(Q0a[3], Q1a[3], Sa[3], (Ma).w);                                    \
    BSTEP(Q0a[2], Q1a[2], Sa[2], (Ma).z);                                    \
    BSTEP(Q0a[1], Q1a[1], Sa[1], (Ma).y);                                    \
    BSTEP(Q0a[0], Q1a[0], Sa[0], (Ma).x);                                    \
    RENORM();                                                                \
} while (0)

// ---- helper: per-seq path score, emission via coalesced float4 scan ----
static __device__ void helper_score(int s, int lane,
                                    const int* __restrict__ tags,
                                    const int* __restrict__ mask,
                                    const float* __restrict__ inputs,
                                    const float* __restrict__ startt,
                                    const float* __restrict__ endt,
                                    const float* tl, int* tagm, float* recs)
{
    const int* tp = tags + (size_t)s * S_;
    const int* mp = mask + (size_t)s * S_;
    const float* ib = inputs + (size_t)s * (S_ * T_);
    const int4* tp4 = (const int4*)tp;
    const int4* mp4 = (const int4*)mp;

    int4 t0 = tp4[2 * lane], t1 = tp4[2 * lane + 1];
    int4 m0 = mp4[2 * lane], m1 = mp4[2 * lane + 1];
    int tg[8] = {t0.x, t0.y, t0.z, t0.w, t1.x, t1.y, t1.z, t1.w};
    int mi[8] = {m0.x, m0.y, m0.z, m0.w, m1.x, m1.y, m1.z, m1.w};
    int tprev = (lane > 0) ? tp[8 * lane - 1] : 0;

    // stage tag|maskbit per row into LDS (coalesced source regs)
    __builtin_amdgcn_wave_barrier();
#pragma unroll
    for (int u = 0; u < 8; ++u) {
        int t = 8 * lane + u;
        tagm[t] = tg[u] | ((mi[u] != 0 && t <= S_ - 2) ? 0x100 : 0);
    }
    __builtin_amdgcn_wave_barrier();

    // transition score + mask count (register path, coalesced loads already)
    float tr = 0.0f;
    int ms = 0;
#pragma unroll
    for (int u = 0; u < 8; ++u) {
        int t = 8 * lane + u;
        int pt = (u == 0) ? tprev : tg[u - 1];
        float tv = tl[pt * T_ + tg[u]];
        tr = fmaf(((t >= 1) && mi[u]) ? 1.0f : 0.0f, tv, tr);
        ms += mi[u];
    }

    // emission: coalesced scan of the whole sequence (34 float4 / lane)
    float e = 0.0f;
    const f4u* iv = (const f4u*)ib;        // 512*17/4 = 2176 float4s
    for (int i = 0; i < 34; ++i) {
        const int v = i * 64 + lane;
        f4u x = iv[v];
        const int f0 = 4 * v;
#pragma unroll
        for (int k = 0; k < 4; ++k) {
            const unsigned f = (unsigned)(f0 + k);
            const unsigned t = f / 17u;
            const unsigned e17 = f - t * 17u;
            const int pk = tagm[t];
            const bool hit = ((pk & 0xff) == (int)e17) && (pk & 0x100);
            const float val = (k == 0) ? x.x : (k == 1) ? x.y : (k == 2) ? x.z : x.w;
            e += hit ? val : 0.0f;
        }
    }

    for (int d = 1; d < 64; d <<= 1) {
        e  += __shfl_xor(e, d);
        tr += __shfl_xor(tr, d);
        ms += __shfl_xor(ms, d);
    }
    if (lane == 0) {
        int li = ms - 1; if (li < 0) li = 0;
        int lt = tp[li];
        float ml = (float)mp[S_ - 1];
        float lin = ib[(size_t)(S_ - 1) * T_ + lt];
        float sc = startt[tp[0]] + tr + e + endt[lt] + lin * ml;
        recs[(size_t)s * RECN + 252] = sc;
    }
}

__global__ __launch_bounds__(64) void crf_seg(
    const float* __restrict__ inputs, const int* __restrict__ tags,
    const int* __restrict__ mask, const float* __restrict__ trans,
    const float* __restrict__ startt, const float* __restrict__ endt,
    float* __restrict__ ws)
{
    __shared__ float tl[T_ * T_];
    __shared__ int tagm[S_];
    const int lane = (int)threadIdx.x;
    const int bid = (int)blockIdx.x;
    for (int k = lane; k < T_ * T_; k += 64) tl[k] = trans[k];
    __syncthreads();

    if (bid < MAINW) {
        const bool isF = (bid < FWDW);
        const int widx = isF ? bid : bid - FWDW;
        const int j = widx >> 6;              // fwd: seg 0..6 ; bwd: seg j+1
        const int sg = widx & 63;
        const int h = lane >> 5;
        const int col = lane & 31;
        const int seq = sg * 32 + col;

        frag_u A1;
#pragma unroll
        for (int wd = 0; wd < 4; ++wd) {
            const int k0 = 8 * h + 2 * wd, k1 = k0 + 1;
            float e0 = 0.0f, e1 = 0.0f;
            if (col < 17) {
                e0 = isF ? __expf(tl[k0 * T_ + col]) : __expf(tl[col * T_ + k0]);
                e1 = isF ? __expf(tl[k1 * T_ + col]) : __expf(tl[col * T_ + k1]);
            }
            A1.u[wd] = pkbf(e0, e1);
        }
        float E16[9];
#pragma unroll
        for (int k = 0; k < 4; ++k) {
            const int r0 = 4 * h + k, r1 = 8 + 4 * h + k;
            E16[k]     = __expf(isF ? tl[16 * T_ + r0] : tl[r0 * T_ + 16]);
            E16[4 + k] = __expf(isF ? tl[16 * T_ + r1] : tl[r1 * T_ + 16]);
        }
        E16[8] = (h == 0) ? __expf(tl[16 * T_ + 16]) : 0.0f;

        v16f zacc;
#pragma unroll
        for (int r = 0; r < 16; ++r) zacc[r] = 0.0f;

        const float* ip = inputs + (size_t)seq * (S_ * T_);
        const int*   mp = mask + (size_t)seq * S_;

        float W0, W1, W2, W3, W4, W5, W6, W7, W8, w16, Z = 0.0f;
        f4u X0[8], X1[8]; float XS[8]; int4 XM0, XM1;
        f4u Y0[8], Y1[8]; float YS[8]; int4 YM0, YM1;

        int off;
        if (isF) {
            if (j == 0) {
                // F0: exact fwd from alpha0, steps t=1..63
                LOADK8(X0, X1, XS, XM0, XM1, 0);
                LOADK8(Y0, Y1, YS, YM0, YM1, 8);
                f4u s0 = *(const f4u*)(startt + 4 * h);
                f4u s1 = *(const f4u*)(startt + 8 + 4 * h);
                W0 = __expf(X0[0].x + s0.x); W1 = __expf(X0[0].y + s0.y);
                W2 = __expf(X0[0].z + s0.z); W3 = __expf(X0[0].w + s0.w);
                W4 = __expf(X1[0].x + s1.x); W5 = __expf(X1[0].y + s1.y);
                W6 = __expf(X1[0].z + s1.z); W7 = __expf(X1[0].w + s1.w);
                W8 = h ? 0.0f : __expf(XS[0] + startt[16]);
                W16SWAP();
                FSTEP(X0[1], X1[1], XS[1], XM0.y);
                FSTEP(X0[2], X1[2], XS[2], XM0.z);
                FSTEP(X0[3], X1[3], XS[3], XM0.w);
                RENORM();
                FSTEP(X0[4], X1[4], XS[4], XM1.x);
                FSTEP(X0[5], X1[5], XS[5], XM1.y);
                FSTEP(X0[6], X1[6], XS[6], XM1.z);
                FSTEP(X0[7], X1[7], XS[7], XM1.w);
                RENORM();
                for (int c = 0; c < 3; ++c) {
                    LOADK8(X0, X1, XS, XM0, XM1, 16 + 16 * c);
                    FCH8(Y0, Y1, YS, YM0, YM1);
                    LOADK8(Y0, Y1, YS, YM0, YM1, 24 + 16 * c);
                    FCH8(X0, X1, XS, XM0, XM1);
                }
                FCH8(Y0, Y1, YS, YM0, YM1);
            } else {
                // Fj: fwd from ones, steps t=64j..64j+63
                const int tb = 64 * j;
                LOADK8(X0, X1, XS, XM0, XM1, tb);
                LOADK8(Y0, Y1, YS, YM0, YM1, tb + 8);
                W0=W1=W2=W3=W4=W5=W6=W7 = 1.0f;
                W8 = h ? 0.0f : 1.0f;
                W16SWAP();
                for (int c = 0; c < 3; ++c) {
                    FCH8(X0, X1, XS, XM0, XM1);
                    LOADK8(X0, X1, XS, XM0, XM1, tb + 16 + 16 * c);
                    FCH8(Y0, Y1, YS, YM0, YM1);
                    LOADK8(Y0, Y1, YS, YM0, YM1, tb + 24 + 16 * c);
                }
                FCH8(X0, X1, XS, XM0, XM1);
                FCH8(Y0, Y1, YS, YM0, YM1);
            }
            off = j * 18;
        } else {
            // Gjb: transpose run, steps t=64jb+63 .. 64jb (jb = j+1)
            const int jb = j + 1;
            const int tb = 64 * jb;
            LOADK8(X0, X1, XS, XM0, XM1, tb + 56);
            LOADK8(Y0, Y1, YS, YM0, YM1, tb + 48);
            if (jb == 7) {
                f4u e0 = *(const f4u*)(endt + 4 * h);
                f4u e1 = *(const f4u*)(endt + 8 + 4 * h);
                W0 = __expf(e0.x); W1 = __expf(e0.y);
                W2 = __expf(e0.z); W3 = __expf(e0.w);
                W4 = __expf(e1.x); W5 = __expf(e1.y);
                W6 = __expf(e1.z); W7 = __expf(e1.w);
                W8 = h ? 0.0f : __expf(endt[16]);
            } else {
                W0=W1=W2=W3=W4=W5=W6=W7 = 1.0f;
                W8 = h ? 0.0f : 1.0f;
            }
            W16SWAP();
            for (int c = 0; c < 3; ++c) {
                BCH8(X0, X1, XS, XM0, XM1);
                LOADK8(X0, X1, XS, XM0, XM1, tb + 40 - 16 * c);
                BCH8(Y0, Y1, YS, YM0, YM1);
                LOADK8(Y0, Y1, YS, YM0, YM1, tb + 32 - 16 * c);
            }
            BCH8(X0, X1, XS, XM0, XM1);
            BCH8(Y0, Y1, YS, YM0, YM1);
            off = 126 + (jb - 1) * 18;
        }

        float* rec = ws + (size_t)seq * RECN + off;
        rec[4*h+0] = W0; rec[4*h+1] = W1; rec[4*h+2] = W2; rec[4*h+3] = W3;
        rec[8+4*h+0] = W4; rec[8+4*h+1] = W5; rec[8+4*h+2] = W6; rec[8+4*h+3] = W7;
        if (h == 0) { rec[16] = W8; rec[17] = Z; }
    } else {
        helper_score(bid - MAINW, lane, tags, mask, inputs, startt, endt,
                     tl, tagm, ws);
    }
}

// ---- combine: one THREAD per sequence, 8 blocks; per-block partial sums ----
__global__ __launch_bounds__(256) void crf_comb(const float* __restrict__ recs,
                                                float* __restrict__ partial)
{
    __shared__ float sm[256];
    const int tid = (int)threadIdx.x;
    const int s = (int)blockIdx.x * 256 + tid;

    float a = 0.0f;
    {
        const float* r = recs + (size_t)s * RECN;
        float zsum = r[17];               // ZF0
        float logn = 0.0f;
#pragma unroll
        for (int j = 1; j <= 7; ++j) {
            const float* G = r + 126 + (j - 1) * 18;
            const float* F = r + (j - 1) * 18;
            float dot = 0.0f;
#pragma unroll
            for (int i = 0; i < T_; ++i) dot = fmaf(G[i], F[i], dot);
            logn += __logf(dot);
            zsum += G[17];
        }
#pragma unroll
        for (int j = 1; j <= 6; ++j) {
            const float* F = r + j * 18;
            float sf = 0.0f;
#pragma unroll
            for (int i = 0; i < T_; ++i) sf += F[i];
            logn -= __logf(sf);
        }
        a = r[252] - (logn + zsum);
    }
    sm[tid] = a;
    __syncthreads();
    for (int k = 128; k >= 1; k >>= 1) {
        if (tid < k) sm[tid] += sm[tid + k];
        __syncthreads();
    }
    if (tid == 0) partial[blockIdx.x] = sm[0];
}

__global__ __launch_bounds__(64) void crf_red(const float* __restrict__ partial,
                                              float* __restrict__ out)
{
    if (threadIdx.x == 0) {
        float s = 0.0f;
#pragma unroll
        for (int i = 0; i < 8; ++i) s += partial[i];
        out[0] = s;
    }
}

extern "C" void kernel_launch(void* const* d_in, const int* in_sizes, int n_in,
                              void* d_out, int out_size, void* d_ws, size_t ws_size,
                              hipStream_t stream)
{
    const float* inputs = (const float*)d_in[0];
    const int*   tags   = (const int*)d_in[1];
    const int*   mask   = (const int*)d_in[2];
    const float* trans  = (const float*)d_in[3];
    const float* startt = (const float*)d_in[4];
    const float* endt   = (const float*)d_in[5];
    float* out = (float*)d_out;
    float* ws  = (float*)d_ws;
    float* partial = ws + (size_t)B_ * RECN;

    crf_seg<<<MAINW + B_, 64, 0, stream>>>(inputs, tags, mask, trans,
                                           startt, endt, ws);
    crf_comb<<<B_ / 256, 256, 0, stream>>>(ws, partial);
    crf_red<<<1, 64, 0, stream>>>(partial, out);
}

// Round 18
// 55.775 us; speedup vs baseline: 1.3391x; 1.3391x over previous
//
#include <hip/hip_runtime.h>

#define B_ 2048
#define S_ 512
#define T_ 17
#define RECN 256
#define FWDW 448          // 7 segments x 64 waves (fwd F0..F6)
#define MAINW 896         // + 7 segments x 64 waves (bwd G1..G7)

typedef float v16f __attribute__((ext_vector_type(16)));
typedef short v8s  __attribute__((ext_vector_type(8)));
typedef float f4u  __attribute__((ext_vector_type(4), aligned(4)));

union frag_u { unsigned u[4]; v8s v; };

static __device__ inline unsigned pkbf(float lo, float hi) {
    unsigned r;
    asm("v_cvt_pk_bf16_f32 %0, %1, %2" : "=v"(r) : "v"(lo), "v"(hi));
    return r;
}

#define PACKB(S0,S1,S2,S3,S4,S5,S6,S7, BOUT) do {                            \
    unsigned P0_ = pkbf(S0, S1), P1_ = pkbf(S2, S3);                         \
    unsigned R0_ = pkbf(S4, S5), R1_ = pkbf(S6, S7);                         \
    auto s0_ = __builtin_amdgcn_permlane32_swap(P0_, R0_, false, false);     \
    auto s1_ = __builtin_amdgcn_permlane32_swap(P1_, R1_, false, false);     \
    BOUT.u[0] = s0_[0]; BOUT.u[1] = s1_[0];                                  \
    BOUT.u[2] = s0_[1]; BOUT.u[3] = s1_[1];                                  \
} while (0)

#define W16SWAP() do {                                                       \
    auto rw_ = __builtin_amdgcn_permlane32_swap(__float_as_uint(W8),         \
                                                __float_as_uint(W8),         \
                                                false, false);               \
    w16 = __uint_as_float(rw_[0]);                                           \
} while (0)

#define LOADK8(Q0, Q1, SS, MA, MB, T0_) do {                                 \
    const float* bp_ = ip + (size_t)(T0_) * T_;                              \
    _Pragma("unroll") for (int u_ = 0; u_ < 8; ++u_) {                       \
        Q0[u_] = *(const f4u*)(bp_ + u_ * T_ + 4 * h);                       \
        Q1[u_] = *(const f4u*)(bp_ + u_ * T_ + 8 + 4 * h);                   \
        SS[u_] = bp_[u_ * T_ + 16];                                          \
    }                                                                        \
    MA = *(const int4*)(mp + (T0_));                                         \
    MB = *(const int4*)(mp + (T0_) + 4);                                     \
} while (0)

#define FSTEP(Q0u, Q1u, Su, Mu) do {                                         \
    frag_u Bf_;                                                              \
    PACKB(W0,W1,W2,W3,W4,W5,W6,W7, Bf_);                                     \
    v16f acc_ = __builtin_amdgcn_mfma_f32_32x32x16_bf16(A1.v, Bf_.v, zacc,0,0,0); \
    float d0_=__expf((Q0u).x), d1_=__expf((Q0u).y);                          \
    float d2_=__expf((Q0u).z), d3_=__expf((Q0u).w);                          \
    float d4_=__expf((Q1u).x), d5_=__expf((Q1u).y);                          \
    float d6_=__expf((Q1u).z), d7_=__expf((Q1u).w);                          \
    float d8_=__expf(Su);                                                    \
    bool bm_ = (Mu) != 0;                                                    \
    float n0_ = fmaf(E16[0], w16, acc_[0]) * d0_;                            \
    float n1_ = fmaf(E16[1], w16, acc_[1]) * d1_;                            \
    float n2_ = fmaf(E16[2], w16, acc_[2]) * d2_;                            \
    float n3_ = fmaf(E16[3], w16, acc_[3]) * d3_;                            \
    float n4_ = fmaf(E16[4], w16, acc_[4]) * d4_;                            \
    float n5_ = fmaf(E16[5], w16, acc_[5]) * d5_;                            \
    float n6_ = fmaf(E16[6], w16, acc_[6]) * d6_;                            \
    float n7_ = fmaf(E16[7], w16, acc_[7]) * d7_;                            \
    float n8_ = fmaf(E16[8], w16, acc_[8]) * d8_;                            \
    W0=bm_?n0_:W0; W1=bm_?n1_:W1; W2=bm_?n2_:W2; W3=bm_?n3_:W3;              \
    W4=bm_?n4_:W4; W5=bm_?n5_:W5; W6=bm_?n6_:W6; W7=bm_?n7_:W7;              \
    W8=bm_?n8_:W8;                                                           \
    W16SWAP();                                                               \
} while (0)

#define BSTEP(Q0u, Q1u, Su, Mu) do {                                         \
    float d0_=__expf((Q0u).x), d1_=__expf((Q0u).y);                          \
    float d2_=__expf((Q0u).z), d3_=__expf((Q0u).w);                          \
    float d4_=__expf((Q1u).x), d5_=__expf((Q1u).y);                          \
    float d6_=__expf((Q1u).z), d7_=__expf((Q1u).w);                          \
    float d8_=__expf(Su);                                                    \
    float U16_ = w16 * d8_;                                                  \
    frag_u Bf_;                                                              \
    PACKB(W0*d0_, W1*d1_, W2*d2_, W3*d3_,                                    \
          W4*d4_, W5*d5_, W6*d6_, W7*d7_, Bf_);                              \
    v16f acc_ = __builtin_amdgcn_mfma_f32_32x32x16_bf16(A1.v, Bf_.v, zacc,0,0,0); \
    bool bm_ = (Mu) != 0;                                                    \
    float n0_ = fmaf(E16[0], U16_, acc_[0]);                                 \
    float n1_ = fmaf(E16[1], U16_, acc_[1]);                                 \
    float n2_ = fmaf(E16[2], U16_, acc_[2]);                                 \
    float n3_ = fmaf(E16[3], U16_, acc_[3]);                                 \
    float n4_ = fmaf(E16[4], U16_, acc_[4]);                                 \
    float n5_ = fmaf(E16[5], U16_, acc_[5]);                                 \
    float n6_ = fmaf(E16[6], U16_, acc_[6]);                                 \
    float n7_ = fmaf(E16[7], U16_, acc_[7]);                                 \
    float n8_ = fmaf(E16[8], U16_, acc_[8]);                                 \
    W0=bm_?n0_:W0; W1=bm_?n1_:W1; W2=bm_?n2_:W2; W3=bm_?n3_:W3;              \
    W4=bm_?n4_:W4; W5=bm_?n5_:W5; W6=bm_?n6_:W6; W7=bm_?n7_:W7;              \
    W8=bm_?n8_:W8;                                                           \
    W16SWAP();                                                               \
} while (0)

#define RENORM() do {                                                        \
    float M_ = fmaxf(fmaxf(fmaxf(W0,W1),fmaxf(W2,W3)),                       \
                     fmaxf(fmaxf(W4,W5),fmaxf(fmaxf(W6,W7),W8)));            \
    auto rm_ = __builtin_amdgcn_permlane32_swap(__float_as_uint(M_),         \
                                                __float_as_uint(M_),         \
                                                false, false);               \
    M_ = fmaxf(__uint_as_float(rm_[0]), __uint_as_float(rm_[1]));            \
    float r_ = 1.0f / M_;                                                    \
    Z += __logf(M_);                                                         \
    W0*=r_; W1*=r_; W2*=r_; W3*=r_; W4*=r_;                                  \
    W5*=r_; W6*=r_; W7*=r_; W8*=r_; w16*=r_;                                 \
} while (0)

#define FCH8(Q0a, Q1a, Sa, Ma, Mb) do {                                      \
    FSTEP(Q0a[0], Q1a[0], Sa[0], (Ma).x);                                    \
    FSTEP(Q0a[1], Q1a[1], Sa[1], (Ma).y);                                    \
    FSTEP(Q0a[2], Q1a[2], Sa[2], (Ma).z);                                    \
    FSTEP(Q0a[3], Q1a[3], Sa[3], (Ma).w);                                    \
    RENORM();                                                                \
    FSTEP(Q0a[4], Q1a[4], Sa[4], (Mb).x);                                    \
    FSTEP(Q0a[5], Q1a[5], Sa[5], (Mb).y);                                    \
    FSTEP(Q0a[6], Q1a[6], Sa[6], (Mb).z);                                    \
    FSTEP(Q0a[7], Q1a[7], Sa[7], (Mb).w);                                    \
    RENORM();                                                                \
} while (0)

#define BCH8(Q0a, Q1a, Sa, Ma, Mb) do {                                      \
    BSTEP(Q0a[7], Q1a[7], Sa[7], (Mb).w);                                    \
    BSTEP(Q0a[6], Q1a[6], Sa[6], (Mb).z);                                    \
    BSTEP(Q0a[5], Q1a[5], Sa[5], (Mb).y);                                    \
    BSTEP(Q0a[4], Q1a[4], Sa[4], (Mb).x);                                    \
    RENORM();                                                                \
    BSTEP(Q0a[3], Q1a[3], Sa[3], (Ma).w);                                    \
    BSTEP(Q0a[2], Q1a[2], Sa[2], (Ma).z);                                    \
    BSTEP(Q0a[1], Q1a[1], Sa[1], (Ma).y);                                    \
    BSTEP(Q0a[0], Q1a[0], Sa[0], (Ma).x);                                    \
    RENORM();                                                                \
} while (0)

static __device__ void helper_score(int s, int lane,
                                    const int* __restrict__ tags,
                                    const int* __restrict__ mask,
                                    const float* __restrict__ inputs,
                                    const float* __restrict__ startt,
                                    const float* __restrict__ endt,
                                    const float* tl, float* recs)
{
    const int* tp = tags + (size_t)s * S_;
    const int* mp = mask + (size_t)s * S_;
    const float* ib = inputs + (size_t)s * (S_ * T_);
    const int4* tp4 = (const int4*)tp;
    const int4* mp4 = (const int4*)mp;

    int4 t0 = tp4[2 * lane], t1 = tp4[2 * lane + 1];
    int4 m0 = mp4[2 * lane], m1 = mp4[2 * lane + 1];
    int tg[8] = {t0.x, t0.y, t0.z, t0.w, t1.x, t1.y, t1.z, t1.w};
    int mi[8] = {m0.x, m0.y, m0.z, m0.w, m1.x, m1.y, m1.z, m1.w};
    int tprev = (lane > 0) ? tp[8 * lane - 1] : 0;

    float e = 0.0f, tr = 0.0f;
    int ms = 0;
#pragma unroll
    for (int u = 0; u < 8; ++u) {
        int t = 8 * lane + u;
        float mf = (float)mi[u];
        float gate = (t <= S_ - 2) ? mf : 0.0f;
        e = fmaf(gate, ib[(size_t)t * T_ + tg[u]], e);
        int pt = (u == 0) ? tprev : tg[u - 1];
        float tv = tl[pt * T_ + tg[u]];
        tr = fmaf((t >= 1) ? mf : 0.0f, tv, tr);
        ms += mi[u];
    }
    for (int d = 1; d < 64; d <<= 1) {
        e  += __shfl_xor(e, d);
        tr += __shfl_xor(tr, d);
        ms += __shfl_xor(ms, d);
    }
    if (lane == 0) {
        int li = ms - 1; if (li < 0) li = 0;
        int lt = tp[li];
        float ml = (float)mp[S_ - 1];
        float lin = ib[(size_t)(S_ - 1) * T_ + lt];
        float sc = startt[tp[0]] + tr + e + endt[lt] + lin * ml;
        recs[(size_t)s * RECN + 252] = sc;
    }
}

__global__ __launch_bounds__(64) void crf_seg(
    const float* __restrict__ inputs, const int* __restrict__ tags,
    const int* __restrict__ mask, const float* __restrict__ trans,
    const float* __restrict__ startt, const float* __restrict__ endt,
    float* __restrict__ ws)
{
    __shared__ float tl[T_ * T_];
    const int lane = (int)threadIdx.x;
    const int bid = (int)blockIdx.x;
    for (int k = lane; k < T_ * T_; k += 64) tl[k] = trans[k];
    __syncthreads();

    if (bid < MAINW) {
        const bool isF = (bid < FWDW);
        const int widx = isF ? bid : bid - FWDW;
        const int j = widx >> 6;              // fwd: seg 0..6 ; bwd: seg j+1
        const int sg = widx & 63;
        const int h = lane >> 5;
        const int col = lane & 31;
        const int seq = sg * 32 + col;

        frag_u A1;
#pragma unroll
        for (int wd = 0; wd < 4; ++wd) {
            const int k0 = 8 * h + 2 * wd, k1 = k0 + 1;
            float e0 = 0.0f, e1 = 0.0f;
            if (col < 17) {
                e0 = isF ? __expf(tl[k0 * T_ + col]) : __expf(tl[col * T_ + k0]);
                e1 = isF ? __expf(tl[k1 * T_ + col]) : __expf(tl[col * T_ + k1]);
            }
            A1.u[wd] = pkbf(e0, e1);
        }
        float E16[9];
#pragma unroll
        for (int k = 0; k < 4; ++k) {
            const int r0 = 4 * h + k, r1 = 8 + 4 * h + k;
            E16[k]     = __expf(isF ? tl[16 * T_ + r0] : tl[r0 * T_ + 16]);
            E16[4 + k] = __expf(isF ? tl[16 * T_ + r1] : tl[r1 * T_ + 16]);
        }
        E16[8] = (h == 0) ? __expf(tl[16 * T_ + 16]) : 0.0f;

        v16f zacc;
#pragma unroll
        for (int r = 0; r < 16; ++r) zacc[r] = 0.0f;

        const float* ip = inputs + (size_t)seq * (S_ * T_);
        const int*   mp = mask + (size_t)seq * S_;

        float W0, W1, W2, W3, W4, W5, W6, W7, W8, w16, Z = 0.0f;
        f4u X0[8], X1[8]; float XS[8]; int4 XM0, XM1;
        f4u Y0[8], Y1[8]; float YS[8]; int4 YM0, YM1;

        int off;
        if (isF) {
            if (j == 0) {
                // F0: exact fwd from alpha0, steps t=1..63
                LOADK8(X0, X1, XS, XM0, XM1, 0);
                LOADK8(Y0, Y1, YS, YM0, YM1, 8);
                f4u s0 = *(const f4u*)(startt + 4 * h);
                f4u s1 = *(const f4u*)(startt + 8 + 4 * h);
                W0 = __expf(X0[0].x + s0.x); W1 = __expf(X0[0].y + s0.y);
                W2 = __expf(X0[0].z + s0.z); W3 = __expf(X0[0].w + s0.w);
                W4 = __expf(X1[0].x + s1.x); W5 = __expf(X1[0].y + s1.y);
                W6 = __expf(X1[0].z + s1.z); W7 = __expf(X1[0].w + s1.w);
                W8 = h ? 0.0f : __expf(XS[0] + startt[16]);
                W16SWAP();
                FSTEP(X0[1], X1[1], XS[1], XM0.y);
                FSTEP(X0[2], X1[2], XS[2], XM0.z);
                FSTEP(X0[3], X1[3], XS[3], XM0.w);
                RENORM();
                FSTEP(X0[4], X1[4], XS[4], XM1.x);
                FSTEP(X0[5], X1[5], XS[5], XM1.y);
                FSTEP(X0[6], X1[6], XS[6], XM1.z);
                FSTEP(X0[7], X1[7], XS[7], XM1.w);
                RENORM();
                for (int c = 0; c < 3; ++c) {
                    LOADK8(X0, X1, XS, XM0, XM1, 16 + 16 * c);
                    FCH8(Y0, Y1, YS, YM0, YM1);
                    LOADK8(Y0, Y1, YS, YM0, YM1, 24 + 16 * c);
                    FCH8(X0, X1, XS, XM0, XM1);
                }
                FCH8(Y0, Y1, YS, YM0, YM1);
            } else {
                // Fj: fwd from ones, steps t=64j..64j+63
                const int tb = 64 * j;
                LOADK8(X0, X1, XS, XM0, XM1, tb);
                LOADK8(Y0, Y1, YS, YM0, YM1, tb + 8);
                W0=W1=W2=W3=W4=W5=W6=W7 = 1.0f;
                W8 = h ? 0.0f : 1.0f;
                W16SWAP();
                for (int c = 0; c < 3; ++c) {
                    FCH8(X0, X1, XS, XM0, XM1);
                    LOADK8(X0, X1, XS, XM0, XM1, tb + 16 + 16 * c);
                    FCH8(Y0, Y1, YS, YM0, YM1);
                    LOADK8(Y0, Y1, YS, YM0, YM1, tb + 24 + 16 * c);
                }
                FCH8(X0, X1, XS, XM0, XM1);
                FCH8(Y0, Y1, YS, YM0, YM1);
            }
            off = j * 18;
        } else {
            // Gjb: transpose run, steps t=64jb+63 .. 64jb (jb = j+1)
            const int jb = j + 1;
            const int tb = 64 * jb;
            LOADK8(X0, X1, XS, XM0, XM1, tb + 56);
            LOADK8(Y0, Y1, YS, YM0, YM1, tb + 48);
            if (jb == 7) {
                f4u e0 = *(const f4u*)(endt + 4 * h);
                f4u e1 = *(const f4u*)(endt + 8 + 4 * h);
                W0 = __expf(e0.x); W1 = __expf(e0.y);
                W2 = __expf(e0.z); W3 = __expf(e0.w);
                W4 = __expf(e1.x); W5 = __expf(e1.y);
                W6 = __expf(e1.z); W7 = __expf(e1.w);
                W8 = h ? 0.0f : __expf(endt[16]);
            } else {
                W0=W1=W2=W3=W4=W5=W6=W7 = 1.0f;
                W8 = h ? 0.0f : 1.0f;
            }
            W16SWAP();
            for (int c = 0; c < 3; ++c) {
                BCH8(X0, X1, XS, XM0, XM1);
                LOADK8(X0, X1, XS, XM0, XM1, tb + 40 - 16 * c);
                BCH8(Y0, Y1, YS, YM0, YM1);
                LOADK8(Y0, Y1, YS, YM0, YM1, tb + 32 - 16 * c);
            }
            BCH8(X0, X1, XS, XM0, XM1);
            BCH8(Y0, Y1, YS, YM0, YM1);
            off = 126 + (jb - 1) * 18;
        }

        float* rec = ws + (size_t)seq * RECN + off;
        rec[4*h+0] = W0; rec[4*h+1] = W1; rec[4*h+2] = W2; rec[4*h+3] = W3;
        rec[8+4*h+0] = W4; rec[8+4*h+1] = W5; rec[8+4*h+2] = W6; rec[8+4*h+3] = W7;
        if (h == 0) { rec[16] = W8; rec[17] = Z; }
    } else {
        helper_score(bid - MAINW, lane, tags, mask, inputs, startt, endt, tl, ws);
    }
}

// ---- combine: one THREAD per sequence, 8 blocks; per-block partial sums ----
__global__ __launch_bounds__(256) void crf_comb(const float* __restrict__ recs,
                                                float* __restrict__ partial)
{
    __shared__ float sm[256];
    const int tid = (int)threadIdx.x;
    const int s = (int)blockIdx.x * 256 + tid;

    float a = 0.0f;
    {
        const float* r = recs + (size_t)s * RECN;
        float zsum = r[17];               // ZF0
        float logn = 0.0f;
#pragma unroll
        for (int j = 1; j <= 7; ++j) {
            const float* G = r + 126 + (j - 1) * 18;
            const float* F = r + (j - 1) * 18;
            float dot = 0.0f;
#pragma unroll
            for (int i = 0; i < T_; ++i) dot = fmaf(G[i], F[i], dot);
            logn += __logf(dot);
            zsum += G[17];
        }
#pragma unroll
        for (int j = 1; j <= 6; ++j) {
            const float* F = r + j * 18;
            float sf = 0.0f;
#pragma unroll
            for (int i = 0; i < T_; ++i) sf += F[i];
            logn -= __logf(sf);
        }
        a = r[252] - (logn + zsum);
    }
    sm[tid] = a;
    __syncthreads();
    for (int k = 128; k >= 1; k >>= 1) {
        if (tid < k) sm[tid] += sm[tid + k];
        __syncthreads();
    }
    if (tid == 0) partial[blockIdx.x] = sm[0];
}

__global__ __launch_bounds__(64) void crf_red(const float* __restrict__ partial,
                                              float* __restrict__ out)
{
    if (threadIdx.x == 0) {
        float s = 0.0f;
#pragma unroll
        for (int i = 0; i < 8; ++i) s += partial[i];
        out[0] = s;
    }
}

extern "C" void kernel_launch(void* const* d_in, const int* in_sizes, int n_in,
                              void* d_out, int out_size, void* d_ws, size_t ws_size,
                              hipStream_t stream)
{
    const float* inputs = (const float*)d_in[0];
    const int*   tags   = (const int*)d_in[1];
    const int*   mask   = (const int*)d_in[2];
    const float* trans  = (const float*)d_in[3];
    const float* startt = (const float*)d_in[4];
    const float* endt   = (const float*)d_in[5];
    float* out = (float*)d_out;
    float* ws  = (float*)d_ws;
    float* partial = ws + (size_t)B_ * RECN;

    crf_seg<<<MAINW + B_, 64, 0, stream>>>(inputs, tags, mask, trans,
                                           startt, endt, ws);
    crf_comb<<<B_ / 256, 256, 0, stream>>>(ws, partial);
    crf_red<<<1, 64, 0, stream>>>(partial, out);
}

// Round 19
// 55.416 us; speedup vs baseline: 1.3478x; 1.0065x over previous
//
#include <hip/hip_runtime.h>

#define B_ 2048
#define S_ 512
#define T_ 17
#define RECN 256
#define FWDW 448          // 7 segments x 64 waves (fwd F0..F6)
#define MAINW 896         // + 7 segments x 64 waves (bwd G1..G7)

typedef float v16f __attribute__((ext_vector_type(16)));
typedef short v8s  __attribute__((ext_vector_type(8)));
typedef float f4u  __attribute__((ext_vector_type(4), aligned(4)));

union frag_u { unsigned u[4]; v8s v; };

static __device__ inline unsigned pkbf(float lo, float hi) {
    unsigned r;
    asm("v_cvt_pk_bf16_f32 %0, %1, %2" : "=v"(r) : "v"(lo), "v"(hi));
    return r;
}

#define PACKB(S0,S1,S2,S3,S4,S5,S6,S7, BOUT) do {                            \
    unsigned P0_ = pkbf(S0, S1), P1_ = pkbf(S2, S3);                         \
    unsigned R0_ = pkbf(S4, S5), R1_ = pkbf(S6, S7);                         \
    auto s0_ = __builtin_amdgcn_permlane32_swap(P0_, R0_, false, false);     \
    auto s1_ = __builtin_amdgcn_permlane32_swap(P1_, R1_, false, false);     \
    BOUT.u[0] = s0_[0]; BOUT.u[1] = s1_[0];                                  \
    BOUT.u[2] = s0_[1]; BOUT.u[3] = s1_[1];                                  \
} while (0)

#define W16SWAP() do {                                                       \
    auto rw_ = __builtin_amdgcn_permlane32_swap(__float_as_uint(W8),         \
                                                __float_as_uint(W8),         \
                                                false, false);               \
    w16 = __uint_as_float(rw_[0]);                                           \
} while (0)

#define LOADK8(Q0, Q1, SS, MA, MB, T0_) do {                                 \
    const float* bp_ = ip + (size_t)(T0_) * T_;                              \
    _Pragma("unroll") for (int u_ = 0; u_ < 8; ++u_) {                       \
        Q0[u_] = *(const f4u*)(bp_ + u_ * T_ + 4 * h);                       \
        Q1[u_] = *(const f4u*)(bp_ + u_ * T_ + 8 + 4 * h);                   \
        SS[u_] = bp_[u_ * T_ + 16];                                          \
    }                                                                        \
    MA = *(const int4*)(mp + (T0_));                                         \
    MB = *(const int4*)(mp + (T0_) + 4);                                     \
} while (0)

// ---- masked (safe) steps ----
#define FSTEP(Q0u, Q1u, Su, Mu) do {                                         \
    frag_u Bf_;                                                              \
    PACKB(W0,W1,W2,W3,W4,W5,W6,W7, Bf_);                                     \
    v16f acc_ = __builtin_amdgcn_mfma_f32_32x32x16_bf16(A1.v, Bf_.v, zacc,0,0,0); \
    float d0_=__expf((Q0u).x), d1_=__expf((Q0u).y);                          \
    float d2_=__expf((Q0u).z), d3_=__expf((Q0u).w);                          \
    float d4_=__expf((Q1u).x), d5_=__expf((Q1u).y);                          \
    float d6_=__expf((Q1u).z), d7_=__expf((Q1u).w);                          \
    float d8_=__expf(Su);                                                    \
    bool bm_ = (Mu) != 0;                                                    \
    float n0_ = fmaf(E16[0], w16, acc_[0]) * d0_;                            \
    float n1_ = fmaf(E16[1], w16, acc_[1]) * d1_;                            \
    float n2_ = fmaf(E16[2], w16, acc_[2]) * d2_;                            \
    float n3_ = fmaf(E16[3], w16, acc_[3]) * d3_;                            \
    float n4_ = fmaf(E16[4], w16, acc_[4]) * d4_;                            \
    float n5_ = fmaf(E16[5], w16, acc_[5]) * d5_;                            \
    float n6_ = fmaf(E16[6], w16, acc_[6]) * d6_;                            \
    float n7_ = fmaf(E16[7], w16, acc_[7]) * d7_;                            \
    float n8_ = fmaf(E16[8], w16, acc_[8]) * d8_;                            \
    W0=bm_?n0_:W0; W1=bm_?n1_:W1; W2=bm_?n2_:W2; W3=bm_?n3_:W3;              \
    W4=bm_?n4_:W4; W5=bm_?n5_:W5; W6=bm_?n6_:W6; W7=bm_?n7_:W7;              \
    W8=bm_?n8_:W8;                                                           \
    W16SWAP();                                                               \
} while (0)

#define BSTEP(Q0u, Q1u, Su, Mu) do {                                         \
    float d0_=__expf((Q0u).x), d1_=__expf((Q0u).y);                          \
    float d2_=__expf((Q0u).z), d3_=__expf((Q0u).w);                          \
    float d4_=__expf((Q1u).x), d5_=__expf((Q1u).y);                          \
    float d6_=__expf((Q1u).z), d7_=__expf((Q1u).w);                          \
    float d8_=__expf(Su);                                                    \
    float U16_ = w16 * d8_;                                                  \
    frag_u Bf_;                                                              \
    PACKB(W0*d0_, W1*d1_, W2*d2_, W3*d3_,                                    \
          W4*d4_, W5*d5_, W6*d6_, W7*d7_, Bf_);                              \
    v16f acc_ = __builtin_amdgcn_mfma_f32_32x32x16_bf16(A1.v, Bf_.v, zacc,0,0,0); \
    bool bm_ = (Mu) != 0;                                                    \
    float n0_ = fmaf(E16[0], U16_, acc_[0]);                                 \
    float n1_ = fmaf(E16[1], U16_, acc_[1]);                                 \
    float n2_ = fmaf(E16[2], U16_, acc_[2]);                                 \
    float n3_ = fmaf(E16[3], U16_, acc_[3]);                                 \
    float n4_ = fmaf(E16[4], U16_, acc_[4]);                                 \
    float n5_ = fmaf(E16[5], U16_, acc_[5]);                                 \
    float n6_ = fmaf(E16[6], U16_, acc_[6]);                                 \
    float n7_ = fmaf(E16[7], U16_, acc_[7]);                                 \
    float n8_ = fmaf(E16[8], U16_, acc_[8]);                                 \
    W0=bm_?n0_:W0; W1=bm_?n1_:W1; W2=bm_?n2_:W2; W3=bm_?n3_:W3;              \
    W4=bm_?n4_:W4; W5=bm_?n5_:W5; W6=bm_?n6_:W6; W7=bm_?n7_:W7;              \
    W8=bm_?n8_:W8;                                                           \
    W16SWAP();                                                               \
} while (0)

// ---- unmasked (fast) steps: arithmetically identical when all masks = 1 ----
#define FSTEPF(Q0u, Q1u, Su) do {                                            \
    frag_u Bf_;                                                              \
    PACKB(W0,W1,W2,W3,W4,W5,W6,W7, Bf_);                                     \
    v16f acc_ = __builtin_amdgcn_mfma_f32_32x32x16_bf16(A1.v, Bf_.v, zacc,0,0,0); \
    float d0_=__expf((Q0u).x), d1_=__expf((Q0u).y);                          \
    float d2_=__expf((Q0u).z), d3_=__expf((Q0u).w);                          \
    float d4_=__expf((Q1u).x), d5_=__expf((Q1u).y);                          \
    float d6_=__expf((Q1u).z), d7_=__expf((Q1u).w);                          \
    float d8_=__expf(Su);                                                    \
    W0 = fmaf(E16[0], w16, acc_[0]) * d0_;                                   \
    W1 = fmaf(E16[1], w16, acc_[1]) * d1_;                                   \
    W2 = fmaf(E16[2], w16, acc_[2]) * d2_;                                   \
    W3 = fmaf(E16[3], w16, acc_[3]) * d3_;                                   \
    W4 = fmaf(E16[4], w16, acc_[4]) * d4_;                                   \
    W5 = fmaf(E16[5], w16, acc_[5]) * d5_;                                   \
    W6 = fmaf(E16[6], w16, acc_[6]) * d6_;                                   \
    W7 = fmaf(E16[7], w16, acc_[7]) * d7_;                                   \
    W8 = fmaf(E16[8], w16, acc_[8]) * d8_;                                   \
    W16SWAP();                                                               \
} while (0)

#define BSTEPF(Q0u, Q1u, Su) do {                                            \
    float d0_=__expf((Q0u).x), d1_=__expf((Q0u).y);                          \
    float d2_=__expf((Q0u).z), d3_=__expf((Q0u).w);                          \
    float d4_=__expf((Q1u).x), d5_=__expf((Q1u).y);                          \
    float d6_=__expf((Q1u).z), d7_=__expf((Q1u).w);                          \
    float d8_=__expf(Su);                                                    \
    float U16_ = w16 * d8_;                                                  \
    frag_u Bf_;                                                              \
    PACKB(W0*d0_, W1*d1_, W2*d2_, W3*d3_,                                    \
          W4*d4_, W5*d5_, W6*d6_, W7*d7_, Bf_);                              \
    v16f acc_ = __builtin_amdgcn_mfma_f32_32x32x16_bf16(A1.v, Bf_.v, zacc,0,0,0); \
    W0 = fmaf(E16[0], U16_, acc_[0]);                                        \
    W1 = fmaf(E16[1], U16_, acc_[1]);                                        \
    W2 = fmaf(E16[2], U16_, acc_[2]);                                        \
    W3 = fmaf(E16[3], U16_, acc_[3]);                                        \
    W4 = fmaf(E16[4], U16_, acc_[4]);                                        \
    W5 = fmaf(E16[5], U16_, acc_[5]);                                        \
    W6 = fmaf(E16[6], U16_, acc_[6]);                                        \
    W7 = fmaf(E16[7], U16_, acc_[7]);                                        \
    W8 = fmaf(E16[8], U16_, acc_[8]);                                        \
    W16SWAP();                                                               \
} while (0)

#define RENORM() do {                                                        \
    float M_ = fmaxf(fmaxf(fmaxf(W0,W1),fmaxf(W2,W3)),                       \
                     fmaxf(fmaxf(W4,W5),fmaxf(fmaxf(W6,W7),W8)));            \
    auto rm_ = __builtin_amdgcn_permlane32_swap(__float_as_uint(M_),         \
                                                __float_as_uint(M_),         \
                                                false, false);               \
    M_ = fmaxf(__uint_as_float(rm_[0]), __uint_as_float(rm_[1]));            \
    float r_ = 1.0f / M_;                                                    \
    Z += __logf(M_);                                                         \
    W0*=r_; W1*=r_; W2*=r_; W3*=r_; W4*=r_;                                  \
    W5*=r_; W6*=r_; W7*=r_; W8*=r_; w16*=r_;                                 \
} while (0)

#define FCH8(Q0a, Q1a, Sa, Ma, Mb) do {                                      \
    FSTEP(Q0a[0], Q1a[0], Sa[0], (Ma).x);                                    \
    FSTEP(Q0a[1], Q1a[1], Sa[1], (Ma).y);                                    \
    FSTEP(Q0a[2], Q1a[2], Sa[2], (Ma).z);                                    \
    FSTEP(Q0a[3], Q1a[3], Sa[3], (Ma).w);                                    \
    RENORM();                                                                \
    FSTEP(Q0a[4], Q1a[4], Sa[4], (Mb).x);                                    \
    FSTEP(Q0a[5], Q1a[5], Sa[5], (Mb).y);                                    \
    FSTEP(Q0a[6], Q1a[6], Sa[6], (Mb).z);                                    \
    FSTEP(Q0a[7], Q1a[7], Sa[7], (Mb).w);                                    \
    RENORM();                                                                \
} while (0)

#define BCH8(Q0a, Q1a, Sa, Ma, Mb) do {                                      \
    BSTEP(Q0a[7], Q1a[7], Sa[7], (Mb).w);                                    \
    BSTEP(Q0a[6], Q1a[6], Sa[6], (Mb).z);                                    \
    BSTEP(Q0a[5], Q1a[5], Sa[5], (Mb).y);                                    \
    BSTEP(Q0a[4], Q1a[4], Sa[4], (Mb).x);                                    \
    RENORM();                                                                \
    BSTEP(Q0a[3], Q1a[3], Sa[3], (Ma).w);                                    \
    BSTEP(Q0a[2], Q1a[2], Sa[2], (Ma).z);                                    \
    BSTEP(Q0a[1], Q1a[1], Sa[1], (Ma).y);                                    \
    BSTEP(Q0a[0], Q1a[0], Sa[0], (Ma).x);                                    \
    RENORM();                                                                \
} while (0)

#define FCH8F(Q0a, Q1a, Sa) do {                                             \
    FSTEPF(Q0a[0], Q1a[0], Sa[0]);                                           \
    FSTEPF(Q0a[1], Q1a[1], Sa[1]);                                           \
    FSTEPF(Q0a[2], Q1a[2], Sa[2]);                                           \
    FSTEPF(Q0a[3], Q1a[3], Sa[3]);                                           \
    RENORM();                                                                \
    FSTEPF(Q0a[4], Q1a[4], Sa[4]);                                           \
    FSTEPF(Q0a[5], Q1a[5], Sa[5]);                                           \
    FSTEPF(Q0a[6], Q1a[6], Sa[6]);                                           \
    FSTEPF(Q0a[7], Q1a[7], Sa[7]);                                           \
    RENORM();                                                                \
} while (0)

#define BCH8F(Q0a, Q1a, Sa) do {                                             \
    BSTEPF(Q0a[7], Q1a[7], Sa[7]);                                           \
    BSTEPF(Q0a[6], Q1a[6], Sa[6]);                                           \
    BSTEPF(Q0a[5], Q1a[5], Sa[5]);                                           \
    BSTEPF(Q0a[4], Q1a[4], Sa[4]);                                           \
    RENORM();                                                                \
    BSTEPF(Q0a[3], Q1a[3], Sa[3]);                                           \
    BSTEPF(Q0a[2], Q1a[2], Sa[2]);                                           \
    BSTEPF(Q0a[1], Q1a[1], Sa[1]);                                           \
    BSTEPF(Q0a[0], Q1a[0], Sa[0]);                                           \
    RENORM();                                                                \
} while (0)

// wave-uniform: all 8 masks set on every lane -> select-free chunk
#define ALLM(MA, MB) __all((((MA).x & (MA).y & (MA).z & (MA).w &             \
                             (MB).x & (MB).y & (MB).z & (MB).w)) != 0)

#define FCH8A(Q0a, Q1a, Sa, Ma, Mb) do {                                     \
    if (ALLM(Ma, Mb)) { FCH8F(Q0a, Q1a, Sa); }                               \
    else              { FCH8(Q0a, Q1a, Sa, Ma, Mb); }                        \
} while (0)

#define BCH8A(Q0a, Q1a, Sa, Ma, Mb) do {                                     \
    if (ALLM(Ma, Mb)) { BCH8F(Q0a, Q1a, Sa); }                               \
    else              { BCH8(Q0a, Q1a, Sa, Ma, Mb); }                        \
} while (0)

static __device__ void helper_score(int s, int lane,
                                    const int* __restrict__ tags,
                                    const int* __restrict__ mask,
                                    const float* __restrict__ inputs,
                                    const float* __restrict__ startt,
                                    const float* __restrict__ endt,
                                    const float* tl, float* recs)
{
    const int* tp = tags + (size_t)s * S_;
    const int* mp = mask + (size_t)s * S_;
    const float* ib = inputs + (size_t)s * (S_ * T_);
    const int4* tp4 = (const int4*)tp;
    const int4* mp4 = (const int4*)mp;

    int4 t0 = tp4[2 * lane], t1 = tp4[2 * lane + 1];
    int4 m0 = mp4[2 * lane], m1 = mp4[2 * lane + 1];
    int tg[8] = {t0.x, t0.y, t0.z, t0.w, t1.x, t1.y, t1.z, t1.w};
    int mi[8] = {m0.x, m0.y, m0.z, m0.w, m1.x, m1.y, m1.z, m1.w};
    int tprev = (lane > 0) ? tp[8 * lane - 1] : 0;

    float e = 0.0f, tr = 0.0f;
    int ms = 0;
#pragma unroll
    for (int u = 0; u < 8; ++u) {
        int t = 8 * lane + u;
        float mf = (float)mi[u];
        float gate = (t <= S_ - 2) ? mf : 0.0f;
        e = fmaf(gate, ib[(size_t)t * T_ + tg[u]], e);
        int pt = (u == 0) ? tprev : tg[u - 1];
        float tv = tl[pt * T_ + tg[u]];
        tr = fmaf((t >= 1) ? mf : 0.0f, tv, tr);
        ms += mi[u];
    }
    for (int d = 1; d < 64; d <<= 1) {
        e  += __shfl_xor(e, d);
        tr += __shfl_xor(tr, d);
        ms += __shfl_xor(ms, d);
    }
    if (lane == 0) {
        int li = ms - 1; if (li < 0) li = 0;
        int lt = tp[li];
        float ml = (float)mp[S_ - 1];
        float lin = ib[(size_t)(S_ - 1) * T_ + lt];
        float sc = startt[tp[0]] + tr + e + endt[lt] + lin * ml;
        recs[(size_t)s * RECN + 252] = sc;
    }
}

__global__ __launch_bounds__(64) void crf_seg(
    const float* __restrict__ inputs, const int* __restrict__ tags,
    const int* __restrict__ mask, const float* __restrict__ trans,
    const float* __restrict__ startt, const float* __restrict__ endt,
    float* __restrict__ ws)
{
    __shared__ float tl[T_ * T_];
    const int lane = (int)threadIdx.x;
    const int bid = (int)blockIdx.x;
    for (int k = lane; k < T_ * T_; k += 64) tl[k] = trans[k];
    __syncthreads();

    if (bid < MAINW) {
        const bool isF = (bid < FWDW);
        const int widx = isF ? bid : bid - FWDW;
        const int j = widx >> 6;              // fwd: seg 0..6 ; bwd: seg j+1
        const int sg = widx & 63;
        const int h = lane >> 5;
        const int col = lane & 31;
        const int seq = sg * 32 + col;

        frag_u A1;
#pragma unroll
        for (int wd = 0; wd < 4; ++wd) {
            const int k0 = 8 * h + 2 * wd, k1 = k0 + 1;
            float e0 = 0.0f, e1 = 0.0f;
            if (col < 17) {
                e0 = isF ? __expf(tl[k0 * T_ + col]) : __expf(tl[col * T_ + k0]);
                e1 = isF ? __expf(tl[k1 * T_ + col]) : __expf(tl[col * T_ + k1]);
            }
            A1.u[wd] = pkbf(e0, e1);
        }
        float E16[9];
#pragma unroll
        for (int k = 0; k < 4; ++k) {
            const int r0 = 4 * h + k, r1 = 8 + 4 * h + k;
            E16[k]     = __expf(isF ? tl[16 * T_ + r0] : tl[r0 * T_ + 16]);
            E16[4 + k] = __expf(isF ? tl[16 * T_ + r1] : tl[r1 * T_ + 16]);
        }
        E16[8] = (h == 0) ? __expf(tl[16 * T_ + 16]) : 0.0f;

        v16f zacc;
#pragma unroll
        for (int r = 0; r < 16; ++r) zacc[r] = 0.0f;

        const float* ip = inputs + (size_t)seq * (S_ * T_);
        const int*   mp = mask + (size_t)seq * S_;

        float W0, W1, W2, W3, W4, W5, W6, W7, W8, w16, Z = 0.0f;
        f4u X0[8], X1[8]; float XS[8]; int4 XM0, XM1;
        f4u Y0[8], Y1[8]; float YS[8]; int4 YM0, YM1;

        int off;
        if (isF) {
            if (j == 0) {
                // F0: exact fwd from alpha0, steps t=1..63
                LOADK8(X0, X1, XS, XM0, XM1, 0);
                LOADK8(Y0, Y1, YS, YM0, YM1, 8);
                f4u s0 = *(const f4u*)(startt + 4 * h);
                f4u s1 = *(const f4u*)(startt + 8 + 4 * h);
                W0 = __expf(X0[0].x + s0.x); W1 = __expf(X0[0].y + s0.y);
                W2 = __expf(X0[0].z + s0.z); W3 = __expf(X0[0].w + s0.w);
                W4 = __expf(X1[0].x + s1.x); W5 = __expf(X1[0].y + s1.y);
                W6 = __expf(X1[0].z + s1.z); W7 = __expf(X1[0].w + s1.w);
                W8 = h ? 0.0f : __expf(XS[0] + startt[16]);
                W16SWAP();
                FSTEP(X0[1], X1[1], XS[1], XM0.y);
                FSTEP(X0[2], X1[2], XS[2], XM0.z);
                FSTEP(X0[3], X1[3], XS[3], XM0.w);
                RENORM();
                FSTEP(X0[4], X1[4], XS[4], XM1.x);
                FSTEP(X0[5], X1[5], XS[5], XM1.y);
                FSTEP(X0[6], X1[6], XS[6], XM1.z);
                FSTEP(X0[7], X1[7], XS[7], XM1.w);
                RENORM();
                for (int c = 0; c < 3; ++c) {
                    LOADK8(X0, X1, XS, XM0, XM1, 16 + 16 * c);
                    FCH8A(Y0, Y1, YS, YM0, YM1);
                    LOADK8(Y0, Y1, YS, YM0, YM1, 24 + 16 * c);
                    FCH8A(X0, X1, XS, XM0, XM1);
                }
                FCH8A(Y0, Y1, YS, YM0, YM1);
            } else {
                // Fj: fwd from ones, steps t=64j..64j+63
                const int tb = 64 * j;
                LOADK8(X0, X1, XS, XM0, XM1, tb);
                LOADK8(Y0, Y1, YS, YM0, YM1, tb + 8);
                W0=W1=W2=W3=W4=W5=W6=W7 = 1.0f;
                W8 = h ? 0.0f : 1.0f;
                W16SWAP();
                for (int c = 0; c < 3; ++c) {
                    FCH8A(X0, X1, XS, XM0, XM1);
                    LOADK8(X0, X1, XS, XM0, XM1, tb + 16 + 16 * c);
                    FCH8A(Y0, Y1, YS, YM0, YM1);
                    LOADK8(Y0, Y1, YS, YM0, YM1, tb + 24 + 16 * c);
                }
                FCH8A(X0, X1, XS, XM0, XM1);
                FCH8A(Y0, Y1, YS, YM0, YM1);
            }
            off = j * 18;
        } else {
            // Gjb: transpose run, steps t=64jb+63 .. 64jb (jb = j+1)
            const int jb = j + 1;
            const int tb = 64 * jb;
            LOADK8(X0, X1, XS, XM0, XM1, tb + 56);
            LOADK8(Y0, Y1, YS, YM0, YM1, tb + 48);
            if (jb == 7) {
                f4u e0 = *(const f4u*)(endt + 4 * h);
                f4u e1 = *(const f4u*)(endt + 8 + 4 * h);
                W0 = __expf(e0.x); W1 = __expf(e0.y);
                W2 = __expf(e0.z); W3 = __expf(e0.w);
                W4 = __expf(e1.x); W5 = __expf(e1.y);
                W6 = __expf(e1.z); W7 = __expf(e1.w);
                W8 = h ? 0.0f : __expf(endt[16]);
            } else {
                W0=W1=W2=W3=W4=W5=W6=W7 = 1.0f;
                W8 = h ? 0.0f : 1.0f;
            }
            W16SWAP();
            for (int c = 0; c < 3; ++c) {
                BCH8A(X0, X1, XS, XM0, XM1);
                LOADK8(X0, X1, XS, XM0, XM1, tb + 40 - 16 * c);
                BCH8A(Y0, Y1, YS, YM0, YM1);
                LOADK8(Y0, Y1, YS, YM0, YM1, tb + 32 - 16 * c);
            }
            BCH8A(X0, X1, XS, XM0, XM1);
            BCH8A(Y0, Y1, YS, YM0, YM1);
            off = 126 + (jb - 1) * 18;
        }

        float* rec = ws + (size_t)seq * RECN + off;
        rec[4*h+0] = W0; rec[4*h+1] = W1; rec[4*h+2] = W2; rec[4*h+3] = W3;
        rec[8+4*h+0] = W4; rec[8+4*h+1] = W5; rec[8+4*h+2] = W6; rec[8+4*h+3] = W7;
        if (h == 0) { rec[16] = W8; rec[17] = Z; }
    } else {
        helper_score(bid - MAINW, lane, tags, mask, inputs, startt, endt, tl, ws);
    }
}

// ---- combine: one THREAD per sequence, 8 blocks; per-block partial sums ----
__global__ __launch_bounds__(256) void crf_comb(const float* __restrict__ recs,
                                                float* __restrict__ partial)
{
    __shared__ float sm[256];
    const int tid = (int)threadIdx.x;
    const int s = (int)blockIdx.x * 256 + tid;

    float a = 0.0f;
    {
        const float* r = recs + (size_t)s * RECN;
        float zsum = r[17];               // ZF0
        float logn = 0.0f;
#pragma unroll
        for (int j = 1; j <= 7; ++j) {
            const float* G = r + 126 + (j - 1) * 18;
            const float* F = r + (j - 1) * 18;
            float dot = 0.0f;
#pragma unroll
            for (int i = 0; i < T_; ++i) dot = fmaf(G[i], F[i], dot);
            logn += __logf(dot);
            zsum += G[17];
        }
#pragma unroll
        for (int j = 1; j <= 6; ++j) {
            const float* F = r + j * 18;
            float sf = 0.0f;
#pragma unroll
            for (int i = 0; i < T_; ++i) sf += F[i];
            logn -= __logf(sf);
        }
        a = r[252] - (logn + zsum);
    }
    sm[tid] = a;
    __syncthreads();
    for (int k = 128; k >= 1; k >>= 1) {
        if (tid < k) sm[tid] += sm[tid + k];
        __syncthreads();
    }
    if (tid == 0) partial[blockIdx.x] = sm[0];
}

__global__ __launch_bounds__(64) void crf_red(const float* __restrict__ partial,
                                              float* __restrict__ out)
{
    if (threadIdx.x == 0) {
        float s = 0.0f;
#pragma unroll
        for (int i = 0; i < 8; ++i) s += partial[i];
        out[0] = s;
    }
}

extern "C" void kernel_launch(void* const* d_in, const int* in_sizes, int n_in,
                              void* d_out, int out_size, void* d_ws, size_t ws_size,
                              hipStream_t stream)
{
    const float* inputs = (const float*)d_in[0];
    const int*   tags   = (const int*)d_in[1];
    const int*   mask   = (const int*)d_in[2];
    const float* trans  = (const float*)d_in[3];
    const float* startt = (const float*)d_in[4];
    const float* endt   = (const float*)d_in[5];
    float* out = (float*)d_out;
    float* ws  = (float*)d_ws;
    float* partial = ws + (size_t)B_ * RECN;

    crf_seg<<<MAINW + B_, 64, 0, stream>>>(inputs, tags, mask, trans,
                                           startt, endt, ws);
    crf_comb<<<B_ / 256, 256, 0, stream>>>(ws, partial);
    crf_red<<<1, 64, 0, stream>>>(partial, out);
}